// Round 5
// baseline (737.672 us; speedup 1.0000x reference)
//
#include <hip/hip_runtime.h>
#include <hip/hip_fp16.h>

// AffineCouplingBlock MI355X — Round 5: occupancy + serial-chain attack.
// NT=2 (32 pts/wave), 2-wave blocks, LDS 17.9KB/block (-> ~8 blocks/CU),
// zero __syncthreads, layer-3 output-dot fused into epilogue (f32).
// B=64,T=4096,C=64,H=W=64,COND=16,IN=81(->96 pad),HID=128.
// comb col layout (K-permuted in prep): [lf 0..63][cond 64..79][z 80][0 81..95]

#define NPTS (64 * 4096)
#define ZSIZE (NPTS * 2)

typedef _Float16 f16x8 __attribute__((ext_vector_type(8)));
typedef float f32x4 __attribute__((ext_vector_type(4)));

// ws layout (halfs): W0f [4][3][8][{hi,lo}x512] | W1f [12][4][8][1024]
#define W0F_HALFS (4 * 3 * 8 * 1024)   // 98304
#define W1F_HALFS (12 * 4 * 8 * 1024)  // 393216

// ---------------------------------------------------------------------------
// Prep: fragmentize weights into per-lane-coalesced fp16 hi/lo chunks.
// Fragment slot (lane=16g+c, j) holds B[k=kt*32+8g+j][n=n0*16+c] = W[n][k'].
// A-frags use the same slot->k map, so any HW k-order bijection cancels.
// ---------------------------------------------------------------------------
__global__ void prep_kernel(const float* __restrict__ W0, const float* __restrict__ W1,
                            _Float16* __restrict__ W0f, _Float16* __restrict__ W1f,
                            float* __restrict__ out_ld) {
    const int t0 = blockIdx.x * blockDim.x + threadIdx.x;
    const int stride = gridDim.x * blockDim.x;
    if (t0 < 64) out_ld[t0] = 0.f;
    // W0: [4][128][81] -> padded K=96, col permutation (new k 0..79 <- old k+1, 80 <- old 0)
    for (int t = t0; t < 4 * 3 * 8 * 64 * 8; t += stride) {
        int j = t & 7, r = t >> 3;
        int l = r & 63; r >>= 6;
        int n0 = r & 7; r >>= 3;
        int kt = r % 3, idx = r / 3;
        int k = kt * 32 + (l >> 4) * 8 + j;
        int n = n0 * 16 + (l & 15);
        float v = 0.f;
        if (k <= 80) {
            int ko = (k < 80) ? (k + 1) : 0;
            v = W0[(idx * 128 + n) * 81 + ko];
        }
        _Float16 hi = (_Float16)v;
        _Float16 lo = (_Float16)(v - (float)hi);
        int base = ((idx * 3 + kt) * 8 + n0) * 1024;
        W0f[base + l * 8 + j] = hi;
        W0f[base + 512 + l * 8 + j] = lo;
    }
    // W1: [12][128][128]
    for (int t = t0; t < 12 * 4 * 8 * 64 * 8; t += stride) {
        int j = t & 7, r = t >> 3;
        int l = r & 63; r >>= 6;
        int n0 = r & 7; r >>= 3;
        int kt = r & 3, m = r >> 2;
        int k = kt * 32 + (l >> 4) * 8 + j;
        int n = n0 * 16 + (l & 15);
        float v = W1[(m * 128 + n) * 128 + k];
        _Float16 hi = (_Float16)v;
        _Float16 lo = (_Float16)(v - (float)hi);
        int base = ((m * 4 + kt) * 8 + n0) * 1024;
        W1f[base + l * 8 + j] = hi;
        W1f[base + 512 + l * 8 + j] = lo;
    }
}

// ---------------------------------------------------------------------------
// MLP building blocks (NT=2). A-frags flat: A[t2*KT+kt], t2 = 16-row tile 0..1.
// ---------------------------------------------------------------------------
template <int KT>
__device__ __forceinline__ void load_bfrag(f16x8* B, const _Float16* __restrict__ wfb,
                                           int n0, int lane) {
#pragma unroll
    for (int kt = 0; kt < KT; ++kt) {
        const _Float16* c2 = wfb + kt * 8192 + n0 * 1024 + lane * 8;
        B[2 * kt] = *(const f16x8*)c2;              // hi
        B[2 * kt + 1] = *(const f16x8*)(c2 + 512);  // lo
    }
}

template <int KT>
__device__ __forceinline__ void mfma_n0(const f16x8* A, const f16x8* B, float bb,
                                        f32x4& acc0, f32x4& acc1) {
    acc0 = (f32x4){bb, bb, bb, bb};
    acc1 = (f32x4){bb, bb, bb, bb};
#pragma unroll
    for (int kt = 0; kt < KT; ++kt) {
        acc0 = __builtin_amdgcn_mfma_f32_16x16x32_f16(A[kt], B[2 * kt], acc0, 0, 0, 0);
        acc1 = __builtin_amdgcn_mfma_f32_16x16x32_f16(A[KT + kt], B[2 * kt], acc1, 0, 0, 0);
        acc0 = __builtin_amdgcn_mfma_f32_16x16x32_f16(A[kt], B[2 * kt + 1], acc0, 0, 0, 0);
        acc1 = __builtin_amdgcn_mfma_f32_16x16x32_f16(A[KT + kt], B[2 * kt + 1], acc1, 0, 0, 0);
    }
}

__device__ __forceinline__ float silu(float v) {
    return v * __builtin_amdgcn_rcpf(1.f + __expf(-v));
}

template <int KT>
__device__ __forceinline__ void compute_n0(const f16x8* A, const f16x8* B,
                                           const float* __restrict__ bias, int n0,
                                           _Float16 (*hrow)[136], int fr, int fg) {
    f32x4 acc0, acc1;
    mfma_n0<KT>(A, B, bias[n0 * 16 + fr], acc0, acc1);
#pragma unroll
    for (int t2 = 0; t2 < 2; ++t2) {
        const f32x4 a = t2 ? acc1 : acc0;
#pragma unroll
        for (int rg = 0; rg < 4; ++rg)
            hrow[t2 * 16 + fg * 4 + rg][n0 * 16 + fr] = (_Float16)silu(a[rg]);
    }
}

// layer-3 variant: no h write; accumulate output dot in f32 regs.
template <int KT>
__device__ __forceinline__ void compute_n0_final(const f16x8* A, const f16x8* B,
                                                 const float* __restrict__ bias, int n0,
                                                 const float* w2v, float* dotp, int fr) {
    f32x4 acc0, acc1;
    mfma_n0<KT>(A, B, bias[n0 * 16 + fr], acc0, acc1);
#pragma unroll
    for (int t2 = 0; t2 < 2; ++t2) {
        const f32x4 a = t2 ? acc1 : acc0;
#pragma unroll
        for (int rg = 0; rg < 4; ++rg)
            dotp[t2 * 4 + rg] = fmaf(silu(a[rg]), w2v[n0], dotp[t2 * 4 + rg]);
    }
}

template <int KT>
__device__ __forceinline__ void run_layer(const f16x8* A, const _Float16* __restrict__ wfb,
                                          const float* __restrict__ bias,
                                          _Float16 (*hrow)[136], int lane, int fr, int fg) {
    f16x8 Ba[2 * KT], Bb[2 * KT];
    load_bfrag<KT>(Ba, wfb, 0, lane);
#pragma unroll
    for (int n0 = 0; n0 < 8; n0 += 2) {
        load_bfrag<KT>(Bb, wfb, n0 + 1, lane);
        compute_n0<KT>(A, Ba, bias, n0, hrow, fr, fg);
        if (n0 + 2 < 8) load_bfrag<KT>(Ba, wfb, n0 + 2, lane);
        compute_n0<KT>(A, Bb, bias, n0 + 1, hrow, fr, fg);
    }
}

template <int KT>
__device__ __forceinline__ void run_layer_final(const f16x8* A, const _Float16* __restrict__ wfb,
                                                const float* __restrict__ bias,
                                                const float* w2v, float* dotp, int lane, int fr) {
    f16x8 Ba[2 * KT], Bb[2 * KT];
    load_bfrag<KT>(Ba, wfb, 0, lane);
#pragma unroll
    for (int n0 = 0; n0 < 8; n0 += 2) {
        load_bfrag<KT>(Bb, wfb, n0 + 1, lane);
        compute_n0_final<KT>(A, Ba, bias, n0, w2v, dotp, fr);
        if (n0 + 2 < 8) load_bfrag<KT>(Ba, wfb, n0 + 2, lane);
        compute_n0_final<KT>(A, Bb, bias, n0 + 1, w2v, dotp, fr);
    }
}

// ---------------------------------------------------------------------------
// Fused kernel: both coupling stages. 2 waves/block, 32 points/wave (NT=2).
// No __syncthreads anywhere; all LDS is wave-private (in-order DS pipe).
// ---------------------------------------------------------------------------
__global__ __launch_bounds__(128, 4) void fused_kernel(
    const float* __restrict__ x, const float* __restrict__ w, const float* __restrict__ cond,
    const _Float16* __restrict__ W0f, const float* __restrict__ b0,
    const _Float16* __restrict__ W1f, const float* __restrict__ b1,
    const float* __restrict__ W2, const float* __restrict__ b2,
    float* __restrict__ out) {
    __shared__ __align__(16) _Float16 hlds[2][32][136];  // 17408 B
    __shared__ float hy[2][2][32];                       // 512 B

    const int o = blockIdx.x;
    const int wg = (o & 7) * 512 + (o >> 3);  // XCD-bijective swizzle (4096 = 8*512)
    const int tid = threadIdx.x;
    const int wv = tid >> 6, lane = tid & 63;
    const int pl = lane & 31;  // local point
    const int hh = lane >> 5;  // channel-half
    const int fr = lane & 15, fg = lane >> 4;
    const int pbase = wg * 64 + wv * 32;
    const int b = wg >> 6;  // 64 blocks (4096 points) per batch

    const float2 xv = *(const float2*)&x[2 * (pbase + pl)];
    const float xa = xv.x, xb = xv.y;
    float za = 0.f, zb = 0.f;

    __half2 cpk[8];
    {
        const float* cb = cond + b * 16;
#pragma unroll
        for (int j = 0; j < 8; ++j) cpk[j] = __floats2half2_rn(cb[2 * j], cb[2 * j + 1]);
    }

    float s_acc = 0.f;

    for (int stage = 0; stage < 2; ++stage) {
        // ---- bilinear gather into comb row pl ----
        const float cx = stage ? za : xa;  // grid x = cur_z[...,0]
        const float cy = xb;               // grid y = z_b (unchanged through stage A)
        const float gx = cx * 2.f - 1.f, gy = cy * 2.f - 1.f;
        const float ixf = (gx + 1.f) * 0.5f * 63.f;
        const float iyf = (gy + 1.f) * 0.5f * 63.f;
        const float ix0f = floorf(ixf), iy0f = floorf(iyf);
        const float ix1f = ix0f + 1.f, iy1f = iy0f + 1.f;
        const float wx1 = ixf - ix0f, wx0 = 1.f - wx1;
        const float wy1 = iyf - iy0f, wy0 = 1.f - wy1;
        const bool vx0 = (ix0f >= 0.f) && (ix0f <= 63.f);
        const bool vx1 = (ix1f >= 0.f) && (ix1f <= 63.f);
        const bool vy0 = (iy0f >= 0.f) && (iy0f <= 63.f);
        const bool vy1 = (iy1f >= 0.f) && (iy1f <= 63.f);
        const float f00 = (vy0 && vx0) ? wy0 * wx0 : 0.f;
        const float f01 = (vy0 && vx1) ? wy0 * wx1 : 0.f;
        const float f10 = (vy1 && vx0) ? wy1 * wx0 : 0.f;
        const float f11 = (vy1 && vx1) ? wy1 * wx1 : 0.f;
        const int xi0 = (int)fminf(fmaxf(ix0f, 0.f), 63.f);
        const int xi1 = (int)fminf(fmaxf(ix1f, 0.f), 63.f);
        const int yi0 = (int)fminf(fmaxf(iy0f, 0.f), 63.f);
        const int yi1 = (int)fminf(fmaxf(iy1f, 0.f), 63.f);
        const int o00 = yi0 * 64 + xi0, o01 = yi0 * 64 + xi1;
        const int o10 = yi1 * 64 + xi0, o11 = yi1 * 64 + xi1;

        const float* wq = w + ((size_t)b << 18) + ((size_t)hh << 17);
#pragma unroll 4
        for (int jj = 0; jj < 16; ++jj) {
            const float* wcA = wq + ((2 * jj) << 12);
            const float* wcB = wcA + 4096;
            const float lfA = f00 * wcA[o00] + f01 * wcA[o01] + f10 * wcA[o10] + f11 * wcA[o11];
            const float lfB = f00 * wcB[o00] + f01 * wcB[o01] + f10 * wcB[o10] + f11 * wcB[o11];
            *(__half2*)&hlds[wv][pl][hh * 32 + 2 * jj] = __floats2half2_rn(lfA, lfB);
        }
        if (hh == 0) {  // cond 64..79, z_keep 80, zeros 81..95
            const float zk = stage ? za : xb;
#pragma unroll
            for (int j2 = 0; j2 < 8; ++j2) *(__half2*)&hlds[wv][pl][64 + 2 * j2] = cpk[j2];
            *(__half2*)&hlds[wv][pl][80] = __floats2half2_rn(zk, 0.f);
#pragma unroll
            for (int j2 = 41; j2 < 48; ++j2)
                *(__half2*)&hlds[wv][pl][2 * j2] = __floats2half2_rn(0.f, 0.f);
        }

        // comb A-frags in regs (feeds layer 0 of BOTH chains; h overwrites comb)
        f16x8 cfr[6];
#pragma unroll
        for (int t2 = 0; t2 < 2; ++t2)
#pragma unroll
            for (int kt = 0; kt < 3; ++kt)
                cfr[t2 * 3 + kt] = *(const f16x8*)&hlds[wv][t2 * 16 + fr][kt * 32 + fg * 8];

        for (int chain = 0; chain < 2; ++chain) {
            const int idx = stage * 2 + chain;
            run_layer<3>(cfr, W0f + idx * 3 * 8192, b0 + idx * 128, hlds[wv], lane, fr, fg);
#pragma unroll
            for (int l = 0; l < 2; ++l) {
                f16x8 afr[8];
#pragma unroll
                for (int t2 = 0; t2 < 2; ++t2)
#pragma unroll
                    for (int kt = 0; kt < 4; ++kt)
                        afr[t2 * 4 + kt] = *(const f16x8*)&hlds[wv][t2 * 16 + fr][kt * 32 + fg * 8];
                run_layer<4>(afr, W1f + (idx * 3 + l) * 4 * 8192, b1 + (idx * 3 + l) * 128,
                             hlds[wv], lane, fr, fg);
            }
            // layer 3 + fused output dot (f32 h3, f32 W2)
            {
                f16x8 afr[8];
#pragma unroll
                for (int t2 = 0; t2 < 2; ++t2)
#pragma unroll
                    for (int kt = 0; kt < 4; ++kt)
                        afr[t2 * 4 + kt] = *(const f16x8*)&hlds[wv][t2 * 16 + fr][kt * 32 + fg * 8];
                float w2v[8];
#pragma unroll
                for (int n0 = 0; n0 < 8; ++n0) w2v[n0] = W2[idx * 128 + n0 * 16 + fr];
                float dotp[8];
#pragma unroll
                for (int i = 0; i < 8; ++i) dotp[i] = 0.f;
                run_layer_final<4>(afr, W1f + (idx * 3 + 2) * 4 * 8192, b1 + (idx * 3 + 2) * 128,
                                   w2v, dotp, lane, fr);
                // reduce over the 16 fr-lanes of this fg group (cols of the dot)
#pragma unroll
                for (int off = 1; off <= 8; off <<= 1)
#pragma unroll
                    for (int i = 0; i < 8; ++i) dotp[i] += __shfl_xor(dotp[i], off);
                if (fr == 0) {
                    const float b2v = b2[idx];
#pragma unroll
                    for (int t2 = 0; t2 < 2; ++t2)
#pragma unroll
                        for (int rg = 0; rg < 4; ++rg)
                            hy[wv][chain][t2 * 16 + fg * 4 + rg] = dotp[t2 * 4 + rg] + b2v;
                }
            }
        }

        // ---- z update + log_det ----
        const float ys = hy[wv][0][pl];
        const float yt = hy[wv][1][pl];
        // tanh(y) = 1 - 2/(exp(2y)+1)
        const float s = 1.5f * (1.f - 2.f * __builtin_amdgcn_rcpf(__expf(2.f * ys) + 1.f));
        if (stage == 0)
            za = fmaf(xa, __expf(s), yt);
        else
            zb = fmaf(xb, __expf(s), yt);
        if (hh == 0) s_acc += s;
    }

    if (hh == 0) *(float2*)&out[2 * (pbase + pl)] = make_float2(za, zb);

    float r = s_acc;
#pragma unroll
    for (int off = 1; off <= 32; off <<= 1) r += __shfl_xor(r, off);
    if (lane == 0) atomicAdd(out + ZSIZE + b, r);
}

// ---------------------------------------------------------------------------
extern "C" void kernel_launch(void* const* d_in, const int* in_sizes, int n_in,
                              void* d_out, int out_size, void* d_ws, size_t ws_size,
                              hipStream_t stream) {
    const float* x = (const float*)d_in[0];
    const float* w = (const float*)d_in[1];
    const float* cond = (const float*)d_in[2];
    const float* W0 = (const float*)d_in[3];
    const float* b0 = (const float*)d_in[4];
    const float* W1 = (const float*)d_in[5];
    const float* b1 = (const float*)d_in[6];
    const float* W2 = (const float*)d_in[7];
    const float* b2 = (const float*)d_in[8];
    float* out = (float*)d_out;

    _Float16* W0f = (_Float16*)d_ws;
    _Float16* W1f = W0f + W0F_HALFS;  // total ~0.94 MB

    prep_kernel<<<256, 256, 0, stream>>>(W0, W1, W0f, W1f, out + ZSIZE);
    fused_kernel<<<4096, 128, 0, stream>>>(x, w, cond, W0f, b0, W1f, b1, W2, b2, out);
}

// Round 7
// 411.246 us; speedup vs baseline: 1.7937x; 1.7937x over previous
//
#include <hip/hip_runtime.h>
#include <hip/hip_fp16.h>

// AffineCouplingBlock MI355X — Round 6 resubmit (round-6 bench was a GPU
// acquisition timeout, no signal). Byte-stream attack:
// (a) w transposed to [B,H,W,C] f32 in prep -> gather line traffic /16.
// (b) t-chains (idx 1,3) use single-fp16 weights (no lo-correction): -25% weight
//     bytes and MFMAs. s-chains keep hi/lo (log_det bias protection).
// NT=2, 2-wave blocks, no __syncthreads in fused kernel, launch_bounds(128,2).
// comb col layout (K-permuted in prep): [lf 0..63][cond 64..79][z 80][0 81..95]

#define NPTS (64 * 4096)
#define ZSIZE (NPTS * 2)

typedef _Float16 f16x8 __attribute__((ext_vector_type(8)));
typedef float f32x4 __attribute__((ext_vector_type(4)));

// ws layout: W0f [4][3][8][{hi512,lo512}] | W1f [12][4][8][1024] | wt [64][64][64][64] f32
#define W0F_HALFS (4 * 3 * 8 * 1024)   // 98304
#define W1F_HALFS (12 * 4 * 8 * 1024)  // 393216
#define WT_BYTES_OFF ((W0F_HALFS + W1F_HALFS) * 2)  // 983040
#define WT_BYTES (64ull * 64 * 64 * 64 * 4)         // 67108864

// ---------------------------------------------------------------------------
// Prep 1: fragmentize MLP weights into per-lane-coalesced fp16 hi/lo chunks.
// Fragment slot (lane=16g+c, j) holds B[k=kt*32+8g+j][n=n0*16+c] = W[n][k'].
// A-frags use the same slot->k map, so any HW k-order bijection cancels.
// ---------------------------------------------------------------------------
__global__ void prep_kernel(const float* __restrict__ W0, const float* __restrict__ W1,
                            _Float16* __restrict__ W0f, _Float16* __restrict__ W1f,
                            float* __restrict__ out_ld) {
    const int t0 = blockIdx.x * blockDim.x + threadIdx.x;
    const int stride = gridDim.x * blockDim.x;
    if (t0 < 64) out_ld[t0] = 0.f;
    // W0: [4][128][81] -> padded K=96, col permutation (new k 0..79 <- old k+1, 80 <- old 0)
    for (int t = t0; t < 4 * 3 * 8 * 64 * 8; t += stride) {
        int j = t & 7, r = t >> 3;
        int l = r & 63; r >>= 6;
        int n0 = r & 7; r >>= 3;
        int kt = r % 3, idx = r / 3;
        int k = kt * 32 + (l >> 4) * 8 + j;
        int n = n0 * 16 + (l & 15);
        float v = 0.f;
        if (k <= 80) {
            int ko = (k < 80) ? (k + 1) : 0;
            v = W0[(idx * 128 + n) * 81 + ko];
        }
        _Float16 hi = (_Float16)v;
        _Float16 lo = (_Float16)(v - (float)hi);
        int base = ((idx * 3 + kt) * 8 + n0) * 1024;
        W0f[base + l * 8 + j] = hi;
        W0f[base + 512 + l * 8 + j] = lo;
    }
    // W1: [12][128][128]
    for (int t = t0; t < 12 * 4 * 8 * 64 * 8; t += stride) {
        int j = t & 7, r = t >> 3;
        int l = r & 63; r >>= 6;
        int n0 = r & 7; r >>= 3;
        int kt = r & 3, m = r >> 2;
        int k = kt * 32 + (l >> 4) * 8 + j;
        int n = n0 * 16 + (l & 15);
        float v = W1[(m * 128 + n) * 128 + k];
        _Float16 hi = (_Float16)v;
        _Float16 lo = (_Float16)(v - (float)hi);
        int base = ((m * 4 + kt) * 8 + n0) * 1024;
        W1f[base + l * 8 + j] = hi;
        W1f[base + 512 + l * 8 + j] = lo;
    }
}

// ---------------------------------------------------------------------------
// Prep 2: transpose w [B,C,H,W] -> wt [B,H,W,C] (f32) via LDS tile.
// Block = (b,y): reads coalesced in x, writes coalesced in c.
// ---------------------------------------------------------------------------
__global__ __launch_bounds__(256) void transpose_w(const float* __restrict__ w,
                                                   float* __restrict__ wt) {
    __shared__ float t[64][65];
    const int by = blockIdx.x;  // b*64 + y
    const int y = by & 63, b = by >> 6;
    const int c4 = threadIdx.x >> 6, xx = threadIdx.x & 63;
    const float* src = w + ((size_t)b << 18) + ((size_t)y << 6);
#pragma unroll
    for (int i = 0; i < 16; ++i) {
        const int c = i * 4 + c4;
        t[c][xx] = src[((size_t)c << 12) + xx];
    }
    __syncthreads();
    float* dst = wt + ((size_t)b << 18) + ((size_t)y << 12);
#pragma unroll
    for (int i = 0; i < 16; ++i) {
        const int xo = i * 4 + c4;
        dst[(xo << 6) + xx] = t[xx][xo];
    }
}

// ---------------------------------------------------------------------------
// MLP building blocks (NT=2). A-frags flat: A[t2*KT+kt], t2 = 16-row tile 0..1.
// LO=true: hi/lo split weights (2 MFMAs per kt per tile); LO=false: hi only.
// ---------------------------------------------------------------------------
template <int KT, bool LO>
__device__ __forceinline__ void load_bfrag(f16x8* B, const _Float16* __restrict__ wfb,
                                           int n0, int lane) {
#pragma unroll
    for (int kt = 0; kt < KT; ++kt) {
        const _Float16* c2 = wfb + kt * 8192 + n0 * 1024 + lane * 8;
        if (LO) {
            B[2 * kt] = *(const f16x8*)c2;
            B[2 * kt + 1] = *(const f16x8*)(c2 + 512);
        } else {
            B[kt] = *(const f16x8*)c2;
        }
    }
}

template <int KT, bool LO>
__device__ __forceinline__ void mfma_n0(const f16x8* A, const f16x8* B, float bb,
                                        f32x4& acc0, f32x4& acc1) {
    acc0 = (f32x4){bb, bb, bb, bb};
    acc1 = (f32x4){bb, bb, bb, bb};
#pragma unroll
    for (int kt = 0; kt < KT; ++kt) {
        const f16x8 bh = B[LO ? 2 * kt : kt];
        acc0 = __builtin_amdgcn_mfma_f32_16x16x32_f16(A[kt], bh, acc0, 0, 0, 0);
        acc1 = __builtin_amdgcn_mfma_f32_16x16x32_f16(A[KT + kt], bh, acc1, 0, 0, 0);
        if (LO) {
            const f16x8 bl = B[2 * kt + 1];
            acc0 = __builtin_amdgcn_mfma_f32_16x16x32_f16(A[kt], bl, acc0, 0, 0, 0);
            acc1 = __builtin_amdgcn_mfma_f32_16x16x32_f16(A[KT + kt], bl, acc1, 0, 0, 0);
        }
    }
}

__device__ __forceinline__ float silu(float v) {
    return v * __builtin_amdgcn_rcpf(1.f + __expf(-v));
}

template <int KT, bool LO>
__device__ __forceinline__ void run_layer(const f16x8* A, const _Float16* __restrict__ wfb,
                                          const float* __restrict__ bias,
                                          _Float16 (*hrow)[136], int lane, int fr, int fg) {
#pragma unroll
    for (int n0 = 0; n0 < 8; ++n0) {
        f16x8 B[LO ? 2 * KT : KT];
        load_bfrag<KT, LO>(B, wfb, n0, lane);
        f32x4 acc0, acc1;
        mfma_n0<KT, LO>(A, B, bias[n0 * 16 + fr], acc0, acc1);
#pragma unroll
        for (int t2 = 0; t2 < 2; ++t2) {
            const f32x4 a = t2 ? acc1 : acc0;
#pragma unroll
            for (int rg = 0; rg < 4; ++rg)
                hrow[t2 * 16 + fg * 4 + rg][n0 * 16 + fr] = (_Float16)silu(a[rg]);
        }
    }
}

// final layer: no h write; fuse output dot (f32 h3, f32 W2) into epilogue.
template <int KT, bool LO>
__device__ __forceinline__ void run_layer_final(const f16x8* A, const _Float16* __restrict__ wfb,
                                                const float* __restrict__ bias,
                                                const float* w2v, float* dotp, int lane, int fr) {
#pragma unroll
    for (int n0 = 0; n0 < 8; ++n0) {
        f16x8 B[LO ? 2 * KT : KT];
        load_bfrag<KT, LO>(B, wfb, n0, lane);
        f32x4 acc0, acc1;
        mfma_n0<KT, LO>(A, B, bias[n0 * 16 + fr], acc0, acc1);
#pragma unroll
        for (int t2 = 0; t2 < 2; ++t2) {
            const f32x4 a = t2 ? acc1 : acc0;
#pragma unroll
            for (int rg = 0; rg < 4; ++rg)
                dotp[t2 * 4 + rg] = fmaf(silu(a[rg]), w2v[n0], dotp[t2 * 4 + rg]);
        }
    }
}

template <bool LO>
__device__ __forceinline__ void mlp_chain(int idx, const f16x8* cfr,
                                          const _Float16* __restrict__ W0f,
                                          const float* __restrict__ b0,
                                          const _Float16* __restrict__ W1f,
                                          const float* __restrict__ b1,
                                          const float* __restrict__ W2,
                                          const float* __restrict__ b2,
                                          _Float16 (*hrow)[136], float* hyrow, int lane, int fr,
                                          int fg) {
    run_layer<3, LO>(cfr, W0f + idx * 3 * 8192, b0 + idx * 128, hrow, lane, fr, fg);
#pragma unroll
    for (int l = 0; l < 2; ++l) {
        f16x8 afr[8];
#pragma unroll
        for (int t2 = 0; t2 < 2; ++t2)
#pragma unroll
            for (int kt = 0; kt < 4; ++kt)
                afr[t2 * 4 + kt] = *(const f16x8*)&hrow[t2 * 16 + fr][kt * 32 + fg * 8];
        run_layer<4, LO>(afr, W1f + (idx * 3 + l) * 4 * 8192, b1 + (idx * 3 + l) * 128, hrow,
                         lane, fr, fg);
    }
    {
        f16x8 afr[8];
#pragma unroll
        for (int t2 = 0; t2 < 2; ++t2)
#pragma unroll
            for (int kt = 0; kt < 4; ++kt)
                afr[t2 * 4 + kt] = *(const f16x8*)&hrow[t2 * 16 + fr][kt * 32 + fg * 8];
        float w2v[8];
#pragma unroll
        for (int n0 = 0; n0 < 8; ++n0) w2v[n0] = W2[idx * 128 + n0 * 16 + fr];
        float dotp[8];
#pragma unroll
        for (int i = 0; i < 8; ++i) dotp[i] = 0.f;
        run_layer_final<4, LO>(afr, W1f + (idx * 3 + 2) * 4 * 8192, b1 + (idx * 3 + 2) * 128,
                               w2v, dotp, lane, fr);
#pragma unroll
        for (int off = 1; off <= 8; off <<= 1)
#pragma unroll
            for (int i = 0; i < 8; ++i) dotp[i] += __shfl_xor(dotp[i], off);
        if (fr == 0) {
            const float b2v = b2[idx];
#pragma unroll
            for (int t2 = 0; t2 < 2; ++t2)
#pragma unroll
                for (int rg = 0; rg < 4; ++rg)
                    hyrow[t2 * 16 + fg * 4 + rg] = dotp[t2 * 4 + rg] + b2v;
        }
    }
}

template <bool FIRST>
__device__ __forceinline__ void tap_acc(float* lf, const float* __restrict__ tp, float f) {
#pragma unroll
    for (int r = 0; r < 8; ++r) {
        const f32x4 v = *(const f32x4*)(tp + 4 * r);
#pragma unroll
        for (int j = 0; j < 4; ++j)
            lf[4 * r + j] = FIRST ? f * v[j] : fmaf(f, v[j], lf[4 * r + j]);
    }
    __builtin_amdgcn_sched_barrier(0);  // cap gather load-hoisting (VGPR control)
}

// ---------------------------------------------------------------------------
// Fused kernel: both coupling stages. 2 waves/block, 32 points/wave (NT=2).
// TR=true: gather from wt [B,H,W,C] f32 (contiguous channels). TR=false: from w.
// ---------------------------------------------------------------------------
template <bool TR>
__global__ __launch_bounds__(128, 2) void fused_kernel(
    const float* __restrict__ x, const float* __restrict__ w, const float* __restrict__ wt,
    const float* __restrict__ cond, const _Float16* __restrict__ W0f,
    const float* __restrict__ b0, const _Float16* __restrict__ W1f,
    const float* __restrict__ b1, const float* __restrict__ W2, const float* __restrict__ b2,
    float* __restrict__ out) {
    __shared__ __align__(16) _Float16 hlds[2][32][136];  // 17408 B
    __shared__ float hy[2][2][32];                       // 512 B

    const int o = blockIdx.x;
    const int wg = (o & 7) * 512 + (o >> 3);  // XCD-bijective swizzle (4096 = 8*512)
    const int tid = threadIdx.x;
    const int wv = tid >> 6, lane = tid & 63;
    const int pl = lane & 31;  // local point
    const int hh = lane >> 5;  // channel-half
    const int fr = lane & 15, fg = lane >> 4;
    const int pbase = wg * 64 + wv * 32;
    const int b = wg >> 6;  // 64 blocks (4096 points) per batch

    const float2 xv = *(const float2*)&x[2 * (pbase + pl)];
    const float xa = xv.x, xb = xv.y;
    float za = 0.f, zb = 0.f;

    __half2 cpk[8];
    {
        const float* cb = cond + b * 16;
#pragma unroll
        for (int j = 0; j < 8; ++j) cpk[j] = __floats2half2_rn(cb[2 * j], cb[2 * j + 1]);
    }

    float s_acc = 0.f;

    for (int stage = 0; stage < 2; ++stage) {
        // ---- bilinear params ----
        const float cx = stage ? za : xa;  // grid x = cur_z[...,0]
        const float cy = xb;               // grid y = z_b (unchanged through stage A)
        const float gx = cx * 2.f - 1.f, gy = cy * 2.f - 1.f;
        const float ixf = (gx + 1.f) * 0.5f * 63.f;
        const float iyf = (gy + 1.f) * 0.5f * 63.f;
        const float ix0f = floorf(ixf), iy0f = floorf(iyf);
        const float ix1f = ix0f + 1.f, iy1f = iy0f + 1.f;
        const float wx1 = ixf - ix0f, wx0 = 1.f - wx1;
        const float wy1 = iyf - iy0f, wy0 = 1.f - wy1;
        const bool vx0 = (ix0f >= 0.f) && (ix0f <= 63.f);
        const bool vx1 = (ix1f >= 0.f) && (ix1f <= 63.f);
        const bool vy0 = (iy0f >= 0.f) && (iy0f <= 63.f);
        const bool vy1 = (iy1f >= 0.f) && (iy1f <= 63.f);
        const float f00 = (vy0 && vx0) ? wy0 * wx0 : 0.f;
        const float f01 = (vy0 && vx1) ? wy0 * wx1 : 0.f;
        const float f10 = (vy1 && vx0) ? wy1 * wx0 : 0.f;
        const float f11 = (vy1 && vx1) ? wy1 * wx1 : 0.f;
        const int xi0 = (int)fminf(fmaxf(ix0f, 0.f), 63.f);
        const int xi1 = (int)fminf(fmaxf(ix1f, 0.f), 63.f);
        const int yi0 = (int)fminf(fmaxf(iy0f, 0.f), 63.f);
        const int yi1 = (int)fminf(fmaxf(iy1f, 0.f), 63.f);
        const int o00 = yi0 * 64 + xi0, o01 = yi0 * 64 + xi1;
        const int o10 = yi1 * 64 + xi0, o11 = yi1 * 64 + xi1;

        if (TR) {
            // contiguous-channel gather: 4 taps x 32ch x f32 per lane
            const float* wtb = wt + ((size_t)b << 18) + hh * 32;
            float lf[32];
            tap_acc<true>(lf, wtb + ((size_t)o00 << 6), f00);
            tap_acc<false>(lf, wtb + ((size_t)o01 << 6), f01);
            tap_acc<false>(lf, wtb + ((size_t)o10 << 6), f10);
            tap_acc<false>(lf, wtb + ((size_t)o11 << 6), f11);
#pragma unroll
            for (int j = 0; j < 16; ++j)
                *(__half2*)&hlds[wv][pl][hh * 32 + 2 * j] =
                    __floats2half2_rn(lf[2 * j], lf[2 * j + 1]);
        } else {
            // fallback: per-channel strided gather from w [B,C,H,W]
            const float* wq = w + ((size_t)b << 18) + ((size_t)hh << 17);
#pragma unroll 4
            for (int jj = 0; jj < 16; ++jj) {
                const float* wcA = wq + ((2 * jj) << 12);
                const float* wcB = wcA + 4096;
                const float lfA =
                    f00 * wcA[o00] + f01 * wcA[o01] + f10 * wcA[o10] + f11 * wcA[o11];
                const float lfB =
                    f00 * wcB[o00] + f01 * wcB[o01] + f10 * wcB[o10] + f11 * wcB[o11];
                *(__half2*)&hlds[wv][pl][hh * 32 + 2 * jj] = __floats2half2_rn(lfA, lfB);
            }
        }
        if (hh == 0) {  // cond 64..79, z_keep 80, zeros 81..95
            const float zk = stage ? za : xb;
#pragma unroll
            for (int j2 = 0; j2 < 8; ++j2) *(__half2*)&hlds[wv][pl][64 + 2 * j2] = cpk[j2];
            *(__half2*)&hlds[wv][pl][80] = __floats2half2_rn(zk, 0.f);
#pragma unroll
            for (int j2 = 41; j2 < 48; ++j2)
                *(__half2*)&hlds[wv][pl][2 * j2] = __floats2half2_rn(0.f, 0.f);
        }

        // comb A-frags in regs (feed layer 0 of BOTH chains; h overwrites comb)
        f16x8 cfr[6];
#pragma unroll
        for (int t2 = 0; t2 < 2; ++t2)
#pragma unroll
            for (int kt = 0; kt < 3; ++kt)
                cfr[t2 * 3 + kt] = *(const f16x8*)&hlds[wv][t2 * 16 + fr][kt * 32 + fg * 8];

        // chain 0 = s (hi/lo weights), chain 1 = t (hi only)
        mlp_chain<true>(stage * 2 + 0, cfr, W0f, b0, W1f, b1, W2, b2, hlds[wv], &hy[wv][0][0],
                        lane, fr, fg);
        mlp_chain<false>(stage * 2 + 1, cfr, W0f, b0, W1f, b1, W2, b2, hlds[wv], &hy[wv][1][0],
                         lane, fr, fg);

        // ---- z update + log_det ----
        const float ys = hy[wv][0][pl];
        const float yt = hy[wv][1][pl];
        const float s = 1.5f * (1.f - 2.f * __builtin_amdgcn_rcpf(__expf(2.f * ys) + 1.f));
        if (stage == 0)
            za = fmaf(xa, __expf(s), yt);
        else
            zb = fmaf(xb, __expf(s), yt);
        if (hh == 0) s_acc += s;
    }

    if (hh == 0) *(float2*)&out[2 * (pbase + pl)] = make_float2(za, zb);

    float r = s_acc;
#pragma unroll
    for (int off = 1; off <= 32; off <<= 1) r += __shfl_xor(r, off);
    if (lane == 0) atomicAdd(out + ZSIZE + b, r);
}

// ---------------------------------------------------------------------------
extern "C" void kernel_launch(void* const* d_in, const int* in_sizes, int n_in,
                              void* d_out, int out_size, void* d_ws, size_t ws_size,
                              hipStream_t stream) {
    const float* x = (const float*)d_in[0];
    const float* w = (const float*)d_in[1];
    const float* cond = (const float*)d_in[2];
    const float* W0 = (const float*)d_in[3];
    const float* b0 = (const float*)d_in[4];
    const float* W1 = (const float*)d_in[5];
    const float* b1 = (const float*)d_in[6];
    const float* W2 = (const float*)d_in[7];
    const float* b2 = (const float*)d_in[8];
    float* out = (float*)d_out;

    _Float16* W0f = (_Float16*)d_ws;
    _Float16* W1f = W0f + W0F_HALFS;
    float* wt = (float*)((char*)d_ws + WT_BYTES_OFF);
    const bool big = ws_size >= (size_t)WT_BYTES_OFF + WT_BYTES;

    prep_kernel<<<256, 256, 0, stream>>>(W0, W1, W0f, W1f, out + ZSIZE);
    if (big) {
        transpose_w<<<4096, 256, 0, stream>>>(w, wt);
        fused_kernel<true><<<4096, 128, 0, stream>>>(x, w, wt, cond, W0f, b0, W1f, b1, W2, b2,
                                                     out);
    } else {
        fused_kernel<false><<<4096, 128, 0, stream>>>(x, w, wt, cond, W0f, b0, W1f, b1, W2, b2,
                                                      out);
    }
}